// Round 1
// baseline (154.982 us; speedup 1.0000x reference)
//
#include <hip/hip_runtime.h>

// GRU recommender: B=32768 samples, T=64 steps, H=16, launch vocab=3.
//
// Structure: 1 wave (64 threads) per block, 4 samples per wave, 16 lanes per
// sample; lane e owns h-element e of its sample. W_hh rows (e, 16+e, 32+e)
// live in 48 VGPRs/lane, pre-scaled so sigmoid/tanh need no extra muls:
//   r/z:  acc init = -log2e*(W_ih@x + b_ih + b_hh)  (from 3-entry LUT in LDS)
//         acc += sum_k (-log2e*W_hh[row][k]) * h[k]
//         gate = rcp(1 + exp2(acc))
//   n:    acc init = 2*log2e*b_hh_n; acc += sum_k (2*log2e*Wn[k])*h[k]
//         y = fma(r, acc, lut_n);  n = 1 - 2*rcp(1 + exp2(y))
// h broadcast across the 16 lanes via double-buffered LDS (write b32, read 4x b128).

#define NB 32768
#define TT 64

static __device__ __forceinline__ float fast_exp2(float x) { return __builtin_amdgcn_exp2f(x); }
static __device__ __forceinline__ float fast_rcp(float x)  { return __builtin_amdgcn_rcpf(x); }

__global__ __launch_bounds__(64) void gru_kernel(
    const int* __restrict__ user_id,
    const int* __restrict__ launch_seq,
    const float* __restrict__ user_emb,
    const float* __restrict__ launch_emb,
    const float* __restrict__ W_ih,
    const float* __restrict__ W_hh,
    const float* __restrict__ b_ih,
    const float* __restrict__ b_hh,
    const float* __restrict__ fc_W,
    const float* __restrict__ fc_b,
    float* __restrict__ out)
{
    constexpr float L  = 1.4426950408889634f;   // log2(e)
    constexpr float L2 = 2.8853900817779268f;   // 2*log2(e)

    __shared__ float4 gx4[3 * 16];      // [s][e] -> {r_pre, z_pre, n_pre, pad}
    __shared__ int    seq_lds[4 * 64];  // [sample j][t]
    __shared__ float4 hbuf[2][16];      // double-buffered h, [sample j] spans 4 float4s

    const int tid = threadIdx.x;
    const int e   = tid & 15;    // h-element index
    const int j   = tid >> 4;    // sample-within-block
    const long long sampBase = (long long)blockIdx.x * 4;

    // ---- build the 3-entry gate-input LUT (144 useful floats) ----
    for (int idx = tid; idx < 144; idx += 64) {
        int s = idx / 48;
        int g = idx - s * 48;
        float dot = b_ih[g];
        #pragma unroll
        for (int k = 0; k < 16; ++k)
            dot = fmaf(W_ih[g * 16 + k], launch_emb[s * 16 + k], dot);
        int ge = g & 15;
        float* dst = (float*)&gx4[s * 16 + ge];
        if (g < 16)       dst[0] = -L * (dot + b_hh[g]);        // r
        else if (g < 32)  dst[1] = -L * (dot + b_hh[g]);        // z
        else              dst[2] =  L2 * dot;                    // n (no b_hh: it is r-scaled)
    }

    // ---- stage this block's launch_seq (256 ints, coalesced) ----
    ((int4*)seq_lds)[tid] = ((const int4*)(launch_seq + sampBase * TT))[tid];

    // ---- per-lane recurrent weights, pre-scaled ----
    float Wr[16], Wz[16], Wn[16];
    #pragma unroll
    for (int k = 0; k < 16; ++k) {
        Wr[k] = -L * W_hh[e * 16 + k];
        Wz[k] = -L * W_hh[(16 + e) * 16 + k];
        Wn[k] =  L2 * W_hh[(32 + e) * 16 + k];
    }
    const float bhn = L2 * b_hh[32 + e];

    // init h buffer 0 (tid == j*16+e exactly covers the 64 floats)
    ((float*)hbuf[0])[tid] = 0.0f;
    float h = 0.0f, pool = 0.0f;
    __syncthreads();

    auto step = [&](const float4* __restrict__ hin, float* __restrict__ hout, int t) {
        int s = seq_lds[j * 64 + t];
        float4 g4 = gx4[s * 16 + e];
        float4 a0 = hin[j * 4 + 0];
        float4 a1 = hin[j * 4 + 1];
        float4 a2 = hin[j * 4 + 2];
        float4 a3 = hin[j * 4 + 3];
        float hv[16] = {a0.x, a0.y, a0.z, a0.w, a1.x, a1.y, a1.z, a1.w,
                        a2.x, a2.y, a2.z, a2.w, a3.x, a3.y, a3.z, a3.w};
        float ar = g4.x, az = g4.y, an = bhn;
        #pragma unroll
        for (int k = 0; k < 16; ++k) {
            ar = fmaf(Wr[k], hv[k], ar);
            az = fmaf(Wz[k], hv[k], az);
            an = fmaf(Wn[k], hv[k], an);
        }
        float r = fast_rcp(1.0f + fast_exp2(ar));
        float z = fast_rcp(1.0f + fast_exp2(az));
        float y = fmaf(r, an, g4.z);
        float q = fast_rcp(1.0f + fast_exp2(y));
        float n = fmaf(-2.0f, q, 1.0f);
        h = fmaf(z, h - n, n);
        pool += h;
        hout[j * 16 + e] = h;
    };

    for (int t = 0; t < TT; t += 2) {
        step(hbuf[0], (float*)hbuf[1], t);
        __syncthreads();
        step(hbuf[1], (float*)hbuf[0], t + 1);
        __syncthreads();
    }

    // ---- epilogue: mean-pool, user-emb gather, FC, 16-lane reduce ----
    pool *= (1.0f / 64.0f);
    int uid = user_id[sampBase + j];
    float u = user_emb[(long long)uid * 16 + e];
    float val = fc_W[e] * u + fc_W[16 + e] * pool;
    val += __shfl_xor(val, 8, 16);
    val += __shfl_xor(val, 4, 16);
    val += __shfl_xor(val, 2, 16);
    val += __shfl_xor(val, 1, 16);
    if (e == 0) out[sampBase + j] = val + fc_b[0];
}

extern "C" void kernel_launch(void* const* d_in, const int* in_sizes, int n_in,
                              void* d_out, int out_size, void* d_ws, size_t ws_size,
                              hipStream_t stream) {
    const int*   user_id    = (const int*)d_in[0];
    const int*   launch_seq = (const int*)d_in[1];
    const float* user_emb   = (const float*)d_in[2];
    const float* launch_emb = (const float*)d_in[3];
    const float* W_ih       = (const float*)d_in[4];
    const float* W_hh       = (const float*)d_in[5];
    const float* b_ih       = (const float*)d_in[6];
    const float* b_hh       = (const float*)d_in[7];
    const float* fc_W       = (const float*)d_in[8];
    const float* fc_b       = (const float*)d_in[9];
    float* out = (float*)d_out;

    gru_kernel<<<dim3(NB / 4), dim3(64), 0, stream>>>(
        user_id, launch_seq, user_emb, launch_emb,
        W_ih, W_hh, b_ih, b_hh, fc_W, fc_b, out);
}

// Round 2
// 145.562 us; speedup vs baseline: 1.0647x; 1.0647x over previous
//
#include <hip/hip_runtime.h>
#include <hip/hip_bf16.h>
#include <string.h>

// GRU recommender via MFMA: B=32768, T=64, H=16, launch vocab=3.
//
// One wave (64 thr) per block handles 16 samples. Per step:
//   gh = h(16x16) @ W_hh^T(16x48)  -> 3 gate-blocks of mfma_f32_16x16x32_bf16,
//   hi/lo bf16 split of both operands (3 MFMA terms per gate block, 9 total)
//   so accuracy stays ~fp32. K=16 real, K=16..31 fed zeros.
// C/D layout (verified m89): col=lane&15 (=h dim), row=(lane>>4)*4+reg (=sample).
// Gates/h-update/pool are elementwise in C layout. Next step's A operand
// (m=lane&15=sample, k=oct*8+j) needs a transpose -> single-wave LDS round
// trip: 8x ds_write_b16 (hi/lo planes), 2x ds_read_b128, with octet swizzle
// chunk=(oct+row+(row>>2))&3 to keep both sides <=2-way (free, m136).
// C-init = gx LUT (vocab=3 -> 3x16 per gate, in LDS), pre-scaled so
// sigmoid = rcp(1+exp2(acc)), tanh = 1-2*rcp(1+exp2(y)) need no extra muls.

#define NBLK 2048  // 32768 / 16 samples per block

typedef __attribute__((ext_vector_type(8))) short short8;
typedef __attribute__((ext_vector_type(4))) float floatx4;

static __device__ __forceinline__ float fexp2(float x) { return __builtin_amdgcn_exp2f(x); }
static __device__ __forceinline__ float frcp(float x)  { return __builtin_amdgcn_rcpf(x); }

static __device__ __forceinline__ unsigned short bf16_bits(float f) {
    __hip_bfloat16 b = __float2bfloat16(f);
    union { __hip_bfloat16 b; unsigned short u; } cv; cv.b = b; return cv.u;
}
static __device__ __forceinline__ float bf16_f32(unsigned short u) {
    unsigned v = ((unsigned)u) << 16; float f; memcpy(&f, &v, 4); return f;
}

__global__ __launch_bounds__(64) void gru_mfma(
    const int* __restrict__ user_id,
    const int* __restrict__ launch_seq,
    const float* __restrict__ user_emb,
    const float* __restrict__ launch_emb,
    const float* __restrict__ W_ih,
    const float* __restrict__ W_hh,
    const float* __restrict__ b_ih,
    const float* __restrict__ b_hh,
    const float* __restrict__ fc_W,
    const float* __restrict__ fc_b,
    float* __restrict__ out)
{
    constexpr float L  = 1.4426950408889634f;   // log2(e)
    constexpr float L2 = 2.8853900817779268f;   // 2*log2(e)

    __shared__ float gxr[48], gxz[48], gxn[48];      // [s*16+d], pre-scaled
    __shared__ unsigned char  seqb[16 * 68];         // row stride 68 (bank spread)
    __shared__ unsigned short hhi[16 * 32];          // [sample][32 bf16] 64B rows, swizzled
    __shared__ unsigned short hlo[16 * 32];          // octets 2,3 stay zero (K pad)

    const int tid  = threadIdx.x;
    const int col  = tid & 15;   // C col = h/gate dim; A row m = sample on reads
    const int quad = tid >> 4;
    const long long sampBase = (long long)blockIdx.x * 16;

    // ---- stage launch_seq as bytes (lane -> row tid>>2, 16-col group tid&3) ----
    {
        int r = tid >> 2, w = tid & 3;
        const int* sp = launch_seq + (sampBase + r) * 64 + w * 16;
        #pragma unroll
        for (int g = 0; g < 4; ++g) {
            int4 v = ((const int4*)sp)[g];
            unsigned pk = (unsigned)v.x | ((unsigned)v.y << 8) |
                          ((unsigned)v.z << 16) | ((unsigned)v.w << 24);
            *(unsigned*)(seqb + r * 68 + w * 16 + g * 4) = pk;
        }
    }

    // ---- gx LUT: 3 launch ids x 48 gates ----
    for (int idx = tid; idx < 144; idx += 64) {
        int s = idx / 48;
        int g = idx - s * 48;
        float dot = b_ih[g];
        #pragma unroll
        for (int k = 0; k < 16; ++k)
            dot = fmaf(W_ih[g * 16 + k], launch_emb[s * 16 + k], dot);
        int d = g & 15;
        if (g < 16)      gxr[s * 16 + d] = -L * (dot + b_hh[g]);
        else if (g < 32) gxz[s * 16 + d] = -L * (dot + b_hh[g]);
        else             gxn[s * 16 + d] =  L2 * dot;   // b_hh_n goes in accn init
    }

    // ---- zero h planes (h0 = 0; also the K-pad octets read as zero forever) ----
    for (int i = tid; i < 256; i += 64) {
        ((unsigned*)hhi)[i] = 0u;
        ((unsigned*)hlo)[i] = 0u;
    }

    // ---- B fragments: W_hh rows, pre-scaled, hi/lo bf16 split ----
    // B[k][n]: n = lane&15 = output dim, k = quad*8+j; k>=16 -> 0
    short8 Brh, Brl, Bzh, Bzl, Bnh, Bnl;
    #pragma unroll
    for (int j = 0; j < 8; ++j) {
        int k = quad * 8 + j;
        float wr = 0.f, wz = 0.f, wn = 0.f;
        if (k < 16) {
            wr = -L  * W_hh[(col)      * 16 + k];
            wz = -L  * W_hh[(16 + col) * 16 + k];
            wn =  L2 * W_hh[(32 + col) * 16 + k];
        }
        unsigned short h;
        h = bf16_bits(wr); Brh[j] = (short)h; Brl[j] = (short)bf16_bits(wr - bf16_f32(h));
        h = bf16_bits(wz); Bzh[j] = (short)h; Bzl[j] = (short)bf16_bits(wz - bf16_f32(h));
        h = bf16_bits(wn); Bnh[j] = (short)h; Bnl[j] = (short)bf16_bits(wn - bf16_f32(h));
    }

    const float bhn = L2 * b_hh[32 + col];
    const floatx4 Cn_init = {bhn, bhn, bhn, bhn};

    // ---- loop-invariant LDS addresses ----
    // A read: row m = col, octet = quad, swizzled chunk
    const int a_off = col * 64 + (((quad + col + (col >> 2)) & 3) << 4);
    int w_off[4], seq_base[4];
    #pragma unroll
    for (int i = 0; i < 4; ++i) {
        int s = quad * 4 + i;                       // this reg's sample row
        w_off[i] = s * 64 + ((((col >> 3) + s + (s >> 2)) & 3) << 4) + (col & 7) * 2;
        seq_base[i] = s * 68;
    }

    floatx4 h    = {0.f, 0.f, 0.f, 0.f};
    floatx4 pool = {0.f, 0.f, 0.f, 0.f};
    short8 Ahi = {0, 0, 0, 0, 0, 0, 0, 0};
    short8 Alo = {0, 0, 0, 0, 0, 0, 0, 0};

    __syncthreads();

    #pragma unroll 4
    for (int t = 0; t < 64; ++t) {
        int s0 = seqb[seq_base[0] + t];
        int s1 = seqb[seq_base[1] + t];
        int s2 = seqb[seq_base[2] + t];
        int s3 = seqb[seq_base[3] + t];

        floatx4 accr, accz;
        accr.x = gxr[(s0 << 4) + col]; accr.y = gxr[(s1 << 4) + col];
        accr.z = gxr[(s2 << 4) + col]; accr.w = gxr[(s3 << 4) + col];
        accz.x = gxz[(s0 << 4) + col]; accz.y = gxz[(s1 << 4) + col];
        accz.z = gxz[(s2 << 4) + col]; accz.w = gxz[(s3 << 4) + col];
        float gn[4];
        gn[0] = gxn[(s0 << 4) + col]; gn[1] = gxn[(s1 << 4) + col];
        gn[2] = gxn[(s2 << 4) + col]; gn[3] = gxn[(s3 << 4) + col];

        accr = __builtin_amdgcn_mfma_f32_16x16x32_bf16(Ahi, Brh, accr, 0, 0, 0);
        accr = __builtin_amdgcn_mfma_f32_16x16x32_bf16(Alo, Brh, accr, 0, 0, 0);
        accr = __builtin_amdgcn_mfma_f32_16x16x32_bf16(Ahi, Brl, accr, 0, 0, 0);
        accz = __builtin_amdgcn_mfma_f32_16x16x32_bf16(Ahi, Bzh, accz, 0, 0, 0);
        accz = __builtin_amdgcn_mfma_f32_16x16x32_bf16(Alo, Bzh, accz, 0, 0, 0);
        accz = __builtin_amdgcn_mfma_f32_16x16x32_bf16(Ahi, Bzl, accz, 0, 0, 0);
        floatx4 accn;
        accn = __builtin_amdgcn_mfma_f32_16x16x32_bf16(Ahi, Bnh, Cn_init, 0, 0, 0);
        accn = __builtin_amdgcn_mfma_f32_16x16x32_bf16(Alo, Bnh, accn, 0, 0, 0);
        accn = __builtin_amdgcn_mfma_f32_16x16x32_bf16(Ahi, Bnl, accn, 0, 0, 0);

        #pragma unroll
        for (int i = 0; i < 4; ++i) {
            float r  = frcp(1.0f + fexp2(accr[i]));
            float z  = frcp(1.0f + fexp2(accz[i]));
            float y  = fmaf(r, accn[i], gn[i]);
            float n  = fmaf(-2.0f, frcp(1.0f + fexp2(y)), 1.0f);
            float hn = fmaf(z, h[i] - n, n);
            h[i] = hn;
            pool[i] += hn;
            unsigned short hb = bf16_bits(hn);
            *(unsigned short*)((char*)hhi + w_off[i]) = hb;
            *(unsigned short*)((char*)hlo + w_off[i]) = bf16_bits(hn - bf16_f32(hb));
        }

        __syncthreads();  // single-wave block: cheap; guarantees write->read visibility
        Ahi = *(const short8*)((const char*)hhi + a_off);
        Alo = *(const short8*)((const char*)hlo + a_off);
    }

    // ---- epilogue: FC over [u, mean(h_t)] ----
    const float fw1 = fc_W[col];
    const float fw2 = fc_W[16 + col] * (1.0f / 64.0f);
    #pragma unroll
    for (int i = 0; i < 4; ++i) {
        int s = quad * 4 + i;
        int uid = user_id[sampBase + s];
        float u = user_emb[(long long)uid * 16 + col];
        float v = fmaf(u, fw1, pool[i] * fw2);
        v += __shfl_xor(v, 1);
        v += __shfl_xor(v, 2);
        v += __shfl_xor(v, 4);
        v += __shfl_xor(v, 8);
        if (col == 0) out[sampBase + s] = v + fc_b[0];
    }
}

extern "C" void kernel_launch(void* const* d_in, const int* in_sizes, int n_in,
                              void* d_out, int out_size, void* d_ws, size_t ws_size,
                              hipStream_t stream) {
    const int*   user_id    = (const int*)d_in[0];
    const int*   launch_seq = (const int*)d_in[1];
    const float* user_emb   = (const float*)d_in[2];
    const float* launch_emb = (const float*)d_in[3];
    const float* W_ih       = (const float*)d_in[4];
    const float* W_hh       = (const float*)d_in[5];
    const float* b_ih       = (const float*)d_in[6];
    const float* b_hh       = (const float*)d_in[7];
    const float* fc_W       = (const float*)d_in[8];
    const float* fc_b       = (const float*)d_in[9];
    float* out = (float*)d_out;

    gru_mfma<<<dim3(NBLK), dim3(64), 0, stream>>>(
        user_id, launch_seq, user_emb, launch_emb,
        W_ih, W_hh, b_ih, b_hh, fc_W, fc_b, out);
}

// Round 3
// 145.057 us; speedup vs baseline: 1.0684x; 1.0035x over previous
//
#include <hip/hip_runtime.h>
#include <hip/hip_bf16.h>
#include <string.h>

// GRU recommender via MFMA: B=32768, T=64, H=16, launch vocab=3.
// One wave per block, 16 samples/wave. Per step: 9x mfma_f32_16x16x32_bf16
// (hi/lo split of h and W_hh, 3 terms per gate; K=16 real, upper K zeros in B).
// R3 changes vs R2:
//  - packed (lo16|hi16) dword h-layout, truncation split: pack = and+sub+v_perm,
//    write = 1 ds_write_b32/reg; A-read = 2x ds_read_b128 + 8 v_perm deinterleave
//  - gx LUT in per-lane VGPRs (vocab=3 -> 9 floats/lane), cndmask select tree
//  - launch_seq transposed in LDS -> 1 broadcast ds_read_b32/step
//  - NO per-step __syncthreads: single-wave block, DS ops from one wave are
//    processed in order, so the A-read after the h-writes sees all lanes'
//    writes. Double buffer kills the cross-iteration WAR hazard.
//  - position swizzle p=(d+4*((row>>1)&3))&15 keeps reads/writes <=2-way.

#define NBLK 2048  // 32768 / 16

typedef __attribute__((ext_vector_type(8))) short   short8;
typedef __attribute__((ext_vector_type(4))) float   floatx4;
typedef __attribute__((ext_vector_type(4))) unsigned uintx4;

static __device__ __forceinline__ float fexp2(float x) { return __builtin_amdgcn_exp2f(x); }
static __device__ __forceinline__ float frcp(float x)  { return __builtin_amdgcn_rcpf(x); }
static __device__ __forceinline__ unsigned f2u(float f) { unsigned u; memcpy(&u, &f, 4); return u; }
static __device__ __forceinline__ float u2f(unsigned u) { float f; memcpy(&f, &u, 4); return f; }
static __device__ __forceinline__ unsigned short bf16_rne(float f) {
    union { __hip_bfloat16 b; unsigned short u; } cv; cv.b = __float2bfloat16(f); return cv.u;
}
static __device__ __forceinline__ float sel3(int c, float a0, float a1, float a2) {
    return c == 0 ? a0 : (c == 1 ? a1 : a2);
}

__global__ __launch_bounds__(64) void gru_mfma(
    const int* __restrict__ user_id,
    const int* __restrict__ launch_seq,
    const float* __restrict__ user_emb,
    const float* __restrict__ launch_emb,
    const float* __restrict__ W_ih,
    const float* __restrict__ W_hh,
    const float* __restrict__ b_ih,
    const float* __restrict__ b_hh,
    const float* __restrict__ fc_W,
    const float* __restrict__ fc_b,
    float* __restrict__ out)
{
    constexpr float L  = 1.4426950408889634f;   // log2(e)
    constexpr float L2 = 2.8853900817779268f;   // 2*log2(e)

    __shared__ float         gxlut[192];   // [g*4 + s], g<48, s<3 (slot 3 pad)
    __shared__ unsigned char seqT[1024];   // [t][sample] codes
    __shared__ unsigned      hlds[512];    // 2 buffers x 16 rows x 16 dwords (lo16|hi16)

    const int tid  = threadIdx.x;
    const int col  = tid & 15;
    const int quad = tid >> 4;
    const long long sampBase = (long long)blockIdx.x * 16;

    // ---- stage launch_seq transposed: seqT[t*16 + sample] ----
    {
        int r = tid >> 2, w = tid & 3;
        const int* sp = launch_seq + (sampBase + r) * 64 + w * 16;
        #pragma unroll
        for (int g = 0; g < 4; ++g) {
            int4 v = ((const int4*)sp)[g];
            int t0 = w * 16 + g * 4;
            seqT[(t0 + 0) * 16 + r] = (unsigned char)v.x;
            seqT[(t0 + 1) * 16 + r] = (unsigned char)v.y;
            seqT[(t0 + 2) * 16 + r] = (unsigned char)v.z;
            seqT[(t0 + 3) * 16 + r] = (unsigned char)v.w;
        }
    }

    // ---- gx LUT: 3 launch ids x 48 gates, pre-scaled ----
    for (int idx = tid; idx < 144; idx += 64) {
        int s = idx / 48, g = idx - s * 48;
        float dot = b_ih[g];
        #pragma unroll
        for (int k = 0; k < 16; ++k)
            dot = fmaf(W_ih[g * 16 + k], launch_emb[s * 16 + k], dot);
        gxlut[g * 4 + s] = (g < 32) ? (-L * (dot + b_hh[g])) : (L2 * dot);
    }

    // ---- B fragments: W_hh rows, pre-scaled, RNE hi/lo split; k>=16 -> 0 ----
    short8 Brh, Brl, Bzh, Bzl, Bnh, Bnl;
    #pragma unroll
    for (int j = 0; j < 8; ++j) {
        int k = quad * 8 + j;
        float wr = 0.f, wz = 0.f, wn = 0.f;
        if (k < 16) {
            wr = -L  * W_hh[(col)      * 16 + k];
            wz = -L  * W_hh[(16 + col) * 16 + k];
            wn =  L2 * W_hh[(32 + col) * 16 + k];
        }
        unsigned short hb;
        hb = bf16_rne(wr); Brh[j] = (short)hb; Brl[j] = (short)bf16_rne(wr - u2f((unsigned)hb << 16));
        hb = bf16_rne(wz); Bzh[j] = (short)hb; Bzl[j] = (short)bf16_rne(wz - u2f((unsigned)hb << 16));
        hb = bf16_rne(wn); Bnh[j] = (short)hb; Bnl[j] = (short)bf16_rne(wn - u2f((unsigned)hb << 16));
    }
    const float bhn = L2 * b_hh[32 + col];
    const floatx4 CnInit = {bhn, bhn, bhn, bhn};

    __syncthreads();   // seqT + gxlut visible

    // ---- per-lane gx values (vocab=3) ----
    float4 vr = *(const float4*)&gxlut[(col)      * 4];
    float4 vz = *(const float4*)&gxlut[(16 + col) * 4];
    float4 vn = *(const float4*)&gxlut[(32 + col) * 4];

    // ---- loop-invariant LDS dword addresses ----
    const int qa = quad & 1;                          // quads 2,3 mirror 0,1 (B zeros kill k>=16)
    const int p0 = ((qa * 8) + 4 * ((col >> 1) & 3)) & 15;
    const int a_dw1 = col * 16 + p0;
    const int a_dw2 = col * 16 + ((p0 + 4) & 15);
    int w_dw[4];
    #pragma unroll
    for (int i = 0; i < 4; ++i) {
        int s = quad * 4 + i;
        w_dw[i] = s * 16 + ((col + 4 * ((s >> 1) & 3)) & 15);
    }

    floatx4 h    = {0.f, 0.f, 0.f, 0.f};
    floatx4 pool = {0.f, 0.f, 0.f, 0.f};
    short8 Ahi = {0, 0, 0, 0, 0, 0, 0, 0};
    short8 Alo = {0, 0, 0, 0, 0, 0, 0, 0};
    unsigned seq_dw = *(const unsigned*)&seqT[quad * 4];   // t = 0

    #pragma unroll 4
    for (int t = 0; t < 64; ++t) {
        const int wb = (t & 1) ? 256 : 0;   // write buffer base (dwords); read A from same

        int c0 = seq_dw & 3, c1 = (seq_dw >> 8) & 3,
            c2 = (seq_dw >> 16) & 3, c3 = (seq_dw >> 24) & 3;
        floatx4 accr = { sel3(c0, vr.x, vr.y, vr.z), sel3(c1, vr.x, vr.y, vr.z),
                         sel3(c2, vr.x, vr.y, vr.z), sel3(c3, vr.x, vr.y, vr.z) };
        floatx4 accz = { sel3(c0, vz.x, vz.y, vz.z), sel3(c1, vz.x, vz.y, vz.z),
                         sel3(c2, vz.x, vz.y, vz.z), sel3(c3, vz.x, vz.y, vz.z) };
        float gn[4]  = { sel3(c0, vn.x, vn.y, vn.z), sel3(c1, vn.x, vn.y, vn.z),
                         sel3(c2, vn.x, vn.y, vn.z), sel3(c3, vn.x, vn.y, vn.z) };

        seq_dw = *(const unsigned*)&seqT[((t + 1) & 63) * 16 + quad * 4];  // prefetch next

        accr = __builtin_amdgcn_mfma_f32_16x16x32_bf16(Ahi, Brh, accr, 0, 0, 0);
        accz = __builtin_amdgcn_mfma_f32_16x16x32_bf16(Ahi, Bzh, accz, 0, 0, 0);
        floatx4 accn = __builtin_amdgcn_mfma_f32_16x16x32_bf16(Ahi, Bnh, CnInit, 0, 0, 0);
        accr = __builtin_amdgcn_mfma_f32_16x16x32_bf16(Alo, Brh, accr, 0, 0, 0);
        accz = __builtin_amdgcn_mfma_f32_16x16x32_bf16(Alo, Bzh, accz, 0, 0, 0);
        accn = __builtin_amdgcn_mfma_f32_16x16x32_bf16(Alo, Bnh, accn, 0, 0, 0);
        accr = __builtin_amdgcn_mfma_f32_16x16x32_bf16(Ahi, Brl, accr, 0, 0, 0);
        accz = __builtin_amdgcn_mfma_f32_16x16x32_bf16(Ahi, Bzl, accz, 0, 0, 0);
        accn = __builtin_amdgcn_mfma_f32_16x16x32_bf16(Ahi, Bnl, accn, 0, 0, 0);

        #pragma unroll
        for (int i = 0; i < 4; ++i) {
            float r  = frcp(1.0f + fexp2(accr[i]));
            float z  = frcp(1.0f + fexp2(accz[i]));
            float y  = fmaf(r, accn[i], gn[i]);
            float n  = fmaf(-2.0f, frcp(1.0f + fexp2(y)), 1.0f);
            float hn = fmaf(z, h[i] - n, n);
            h[i] = hn;
            pool[i] += hn;
            unsigned u  = f2u(hn);
            float  lof  = hn - u2f(u & 0xffff0000u);            // exact residual
            hlds[wb + w_dw[i]] = __builtin_amdgcn_perm(f2u(lof), u, 0x07060302u);
        }

        // A for t+1: single-wave in-order DS => reads see this step's writes
        uintx4 A1 = *(const uintx4*)&hlds[wb + a_dw1];
        uintx4 A2 = *(const uintx4*)&hlds[wb + a_dw2];
        uintx4 hi4 = { __builtin_amdgcn_perm(A1.y, A1.x, 0x05040100u),
                       __builtin_amdgcn_perm(A1.w, A1.z, 0x05040100u),
                       __builtin_amdgcn_perm(A2.y, A2.x, 0x05040100u),
                       __builtin_amdgcn_perm(A2.w, A2.z, 0x05040100u) };
        uintx4 lo4 = { __builtin_amdgcn_perm(A1.y, A1.x, 0x07060302u),
                       __builtin_amdgcn_perm(A1.w, A1.z, 0x07060302u),
                       __builtin_amdgcn_perm(A2.y, A2.x, 0x07060302u),
                       __builtin_amdgcn_perm(A2.w, A2.z, 0x07060302u) };
        Ahi = __builtin_bit_cast(short8, hi4);
        Alo = __builtin_bit_cast(short8, lo4);
    }

    // ---- epilogue: FC over [u, mean(h_t)] ----
    const float fw1 = fc_W[col];
    const float fw2 = fc_W[16 + col] * (1.0f / 64.0f);
    #pragma unroll
    for (int i = 0; i < 4; ++i) {
        int s = quad * 4 + i;
        int uid = user_id[sampBase + s];
        float u = user_emb[(long long)uid * 16 + col];
        float v = fmaf(u, fw1, pool[i] * fw2);
        v += __shfl_xor(v, 1);
        v += __shfl_xor(v, 2);
        v += __shfl_xor(v, 4);
        v += __shfl_xor(v, 8);
        if (col == 0) out[sampBase + s] = v + fc_b[0];
    }
}

extern "C" void kernel_launch(void* const* d_in, const int* in_sizes, int n_in,
                              void* d_out, int out_size, void* d_ws, size_t ws_size,
                              hipStream_t stream) {
    const int*   user_id    = (const int*)d_in[0];
    const int*   launch_seq = (const int*)d_in[1];
    const float* user_emb   = (const float*)d_in[2];
    const float* launch_emb = (const float*)d_in[3];
    const float* W_ih       = (const float*)d_in[4];
    const float* W_hh       = (const float*)d_in[5];
    const float* b_ih       = (const float*)d_in[6];
    const float* b_hh       = (const float*)d_in[7];
    const float* fc_W       = (const float*)d_in[8];
    const float* fc_b       = (const float*)d_in[9];
    float* out = (float*)d_out;

    gru_mfma<<<dim3(NBLK), dim3(64), 0, stream>>>(
        user_id, launch_seq, user_emb, launch_emb,
        W_ih, W_hh, b_ih, b_hh, fc_W, fc_b, out);
}

// Round 4
// 138.113 us; speedup vs baseline: 1.1221x; 1.0503x over previous
//
#include <hip/hip_runtime.h>
#include <hip/hip_bf16.h>
#include <string.h>

// GRU recommender via MFMA, R4: B=32768, T=64, H=16, launch vocab=3.
// One wave per block, 16 samples/wave.
//
// Orientation flip vs R3: D[g][s] = sum_d W[g][d] h[d][s]
//   A = W_hh fragments (static, pre-scaled, hi/lo split; octets 2,3 ZERO)
//   B = h fragments (hi/lo), rebuilt per step via 8x ds_bpermute (no LDS
//       store->load round trip, no bank conflicts, no barriers).
// C/D layout: col=lane&15 = sample, row=quad*4+reg = gate/h dim. Each lane
// owns 4 h-dims of one sample; pack pairs into (lo16|hi16)-style bf16 dwords
// in-lane (4 v_perm), then B frag = 4 bpermute pulls: dims 4q..4q+3 live in
// lane col+16q; dest lane col+16*oct needs q=2*(oct&1), 2*(oct&1)+1.
// B octets 2,3 pull mirrored garbage -> killed by A octets 2,3 = 0.
// gx C-init: per-lane VGPR LUT (3 codes x 4 dims x 3 gates = 36 regs),
// selected by the per-sample seq code (1 prefetched ds_read_u8/step).
// Numerics (as R3, absmax ~1e-3): 9 MFMAs/step = 3 gates x (WhiBhi + WloBhi
// + WhiBlo), pre-scaled so sigmoid = rcp(1+exp2(.)), tanh = 1-2*rcp(1+exp2(.)).

#define NBLK 2048  // 32768 / 16

typedef __attribute__((ext_vector_type(8))) short    short8;
typedef __attribute__((ext_vector_type(4))) float    floatx4;
typedef __attribute__((ext_vector_type(4))) unsigned uintx4;

static __device__ __forceinline__ float fexp2(float x) { return __builtin_amdgcn_exp2f(x); }
static __device__ __forceinline__ float frcp(float x)  { return __builtin_amdgcn_rcpf(x); }
static __device__ __forceinline__ unsigned f2u(float f) { unsigned u; memcpy(&u, &f, 4); return u; }
static __device__ __forceinline__ float u2f(unsigned u) { float f; memcpy(&f, &u, 4); return f; }
static __device__ __forceinline__ float sel3(int c, float a0, float a1, float a2) {
    return c == 0 ? a0 : (c == 1 ? a1 : a2);
}

__global__ __launch_bounds__(64) void gru_mfma(
    const int* __restrict__ user_id,
    const int* __restrict__ launch_seq,
    const float* __restrict__ user_emb,
    const float* __restrict__ launch_emb,
    const float* __restrict__ W_ih,
    const float* __restrict__ W_hh,
    const float* __restrict__ b_ih,
    const float* __restrict__ b_hh,
    const float* __restrict__ fc_W,
    const float* __restrict__ fc_b,
    float* __restrict__ out)
{
    constexpr float L  = 1.4426950408889634f;   // log2(e)
    constexpr float L2 = 2.8853900817779268f;   // 2*log2(e)

    __shared__ float         gxlut[144];    // [(gate*3+code)*16 + dim]
    __shared__ unsigned char seqT[1024];    // [t*16 + sample]

    const int tid  = threadIdx.x;
    const int col  = tid & 15;    // sample (B n-index and C/D col)
    const int quad = tid >> 4;
    const long long sampBase = (long long)blockIdx.x * 16;

    // ---- stage launch_seq transposed: seqT[t*16 + sample] ----
    {
        int r = tid >> 2, w = tid & 3;
        const int* sp = launch_seq + (sampBase + r) * 64 + w * 16;
        #pragma unroll
        for (int g = 0; g < 4; ++g) {
            int4 v = ((const int4*)sp)[g];
            int t0 = w * 16 + g * 4;
            seqT[(t0 + 0) * 16 + r] = (unsigned char)v.x;
            seqT[(t0 + 1) * 16 + r] = (unsigned char)v.y;
            seqT[(t0 + 2) * 16 + r] = (unsigned char)v.z;
            seqT[(t0 + 3) * 16 + r] = (unsigned char)v.w;
        }
    }

    // ---- gx LUT: 3 codes x 48 gates, pre-scaled ----
    for (int idx = tid; idx < 144; idx += 64) {
        int s = idx / 48, g = idx - s * 48;
        float dot = b_ih[g];
        #pragma unroll
        for (int k = 0; k < 16; ++k)
            dot = fmaf(W_ih[g * 16 + k], launch_emb[s * 16 + k], dot);
        int gate = g >> 4, dim = g & 15;
        gxlut[(gate * 3 + s) * 16 + dim] =
            (g < 32) ? (-L * (dot + b_hh[g])) : (L2 * dot);
    }

    // ---- A fragments: W_hh rows, pre-scaled, truncation hi/lo split ----
    // A[m][k]: m = lane&15 = gate dim, k = quad*8+j. quads 2,3 -> ZERO
    // (this also annihilates the garbage B pulls in octets 2,3).
    short8 Wrh, Wrl, Wzh, Wzl, Wnh, Wnl;
    {
        auto makeW = [&](int goff, float scale, short8& Hi, short8& Lo) {
            float w[8];
            if (quad < 2) {
                const float* row = W_hh + (goff + col) * 16 + quad * 8;
                float4 a = *(const float4*)row;
                float4 b = *(const float4*)(row + 4);
                w[0] = scale * a.x; w[1] = scale * a.y; w[2] = scale * a.z; w[3] = scale * a.w;
                w[4] = scale * b.x; w[5] = scale * b.y; w[6] = scale * b.z; w[7] = scale * b.w;
            } else {
                #pragma unroll
                for (int j = 0; j < 8; ++j) w[j] = 0.f;
            }
            uintx4 hi, lo;
            #pragma unroll
            for (int p = 0; p < 4; ++p) {
                unsigned u0 = f2u(w[2 * p]), u1 = f2u(w[2 * p + 1]);
                hi[p] = __builtin_amdgcn_perm(u1, u0, 0x07060302u);
                float l0 = w[2 * p]     - u2f(u0 & 0xffff0000u);
                float l1 = w[2 * p + 1] - u2f(u1 & 0xffff0000u);
                lo[p] = __builtin_amdgcn_perm(f2u(l1), f2u(l0), 0x07060302u);
            }
            Hi = __builtin_bit_cast(short8, hi);
            Lo = __builtin_bit_cast(short8, lo);
        };
        makeW(0,  -L, Wrh, Wrl);
        makeW(16, -L, Wzh, Wzl);
        makeW(32,  L2, Wnh, Wnl);
    }

    // n-gate C-init: L2 * b_hh_n for this lane's 4 dims (rows quad*4..+3)
    floatx4 CnInit;
    {
        float4 bh = *(const float4*)&b_hh[32 + quad * 4];
        CnInit = floatx4{L2 * bh.x, L2 * bh.y, L2 * bh.z, L2 * bh.w};
    }

    __syncthreads();   // gxlut + seqT visible

    // ---- per-lane gx LUT in VGPRs: 3 gates x 3 codes x (my 4 dims) ----
    floatx4 gr0 = *(const floatx4*)&gxlut[(0 * 3 + 0) * 16 + quad * 4];
    floatx4 gr1 = *(const floatx4*)&gxlut[(0 * 3 + 1) * 16 + quad * 4];
    floatx4 gr2 = *(const floatx4*)&gxlut[(0 * 3 + 2) * 16 + quad * 4];
    floatx4 gz0 = *(const floatx4*)&gxlut[(1 * 3 + 0) * 16 + quad * 4];
    floatx4 gz1 = *(const floatx4*)&gxlut[(1 * 3 + 1) * 16 + quad * 4];
    floatx4 gz2 = *(const floatx4*)&gxlut[(1 * 3 + 2) * 16 + quad * 4];
    floatx4 gn0 = *(const floatx4*)&gxlut[(2 * 3 + 0) * 16 + quad * 4];
    floatx4 gn1 = *(const floatx4*)&gxlut[(2 * 3 + 1) * 16 + quad * 4];
    floatx4 gn2 = *(const floatx4*)&gxlut[(2 * 3 + 2) * 16 + quad * 4];

    // bpermute source addresses (loop-invariant): dims 8o'..+3 live in lane
    // col+32*o', dims 8o'+4..+7 in lane col+32*o'+16, o' = quad&1.
    const int a1 = (col + 32 * (quad & 1)) * 4;
    const int a2 = a1 + 64;

    floatx4 h    = {0.f, 0.f, 0.f, 0.f};
    floatx4 pool = {0.f, 0.f, 0.f, 0.f};
    short8 Bhi = {0, 0, 0, 0, 0, 0, 0, 0};   // h0 = 0
    short8 Blo = {0, 0, 0, 0, 0, 0, 0, 0};
    int c = seqT[col];                        // code for t = 0

    #pragma unroll 4
    for (int t = 0; t < 64; ++t) {
        floatx4 accr, accz, gnv;
        #pragma unroll
        for (int i = 0; i < 4; ++i) {
            accr[i] = sel3(c, gr0[i], gr1[i], gr2[i]);
            accz[i] = sel3(c, gz0[i], gz1[i], gz2[i]);
            gnv[i]  = sel3(c, gn0[i], gn1[i], gn2[i]);
        }
        int cn = seqT[((t + 1) & 63) * 16 + col];   // prefetch next code

        accr = __builtin_amdgcn_mfma_f32_16x16x32_bf16(Wrh, Bhi, accr, 0, 0, 0);
        accz = __builtin_amdgcn_mfma_f32_16x16x32_bf16(Wzh, Bhi, accz, 0, 0, 0);
        floatx4 accn = __builtin_amdgcn_mfma_f32_16x16x32_bf16(Wnh, Bhi, CnInit, 0, 0, 0);
        accr = __builtin_amdgcn_mfma_f32_16x16x32_bf16(Wrl, Bhi, accr, 0, 0, 0);
        accz = __builtin_amdgcn_mfma_f32_16x16x32_bf16(Wzl, Bhi, accz, 0, 0, 0);
        accn = __builtin_amdgcn_mfma_f32_16x16x32_bf16(Wnl, Bhi, accn, 0, 0, 0);
        accr = __builtin_amdgcn_mfma_f32_16x16x32_bf16(Wrh, Blo, accr, 0, 0, 0);
        accz = __builtin_amdgcn_mfma_f32_16x16x32_bf16(Wzh, Blo, accz, 0, 0, 0);
        accn = __builtin_amdgcn_mfma_f32_16x16x32_bf16(Wnh, Blo, accn, 0, 0, 0);

        #pragma unroll
        for (int i = 0; i < 4; ++i) {
            float r  = frcp(1.0f + fexp2(accr[i]));
            float z  = frcp(1.0f + fexp2(accz[i]));
            float y  = fmaf(r, accn[i], gnv[i]);
            float n  = fmaf(-2.0f, frcp(1.0f + fexp2(y)), 1.0f);
            float hn = fmaf(z, h[i] - n, n);
            h[i] = hn;
            pool[i] += hn;
        }

        // pack this lane's 4 dims: (even dim low16 | odd dim high16), hi+lo planes
        unsigned u0 = f2u(h[0]), u1 = f2u(h[1]), u2 = f2u(h[2]), u3 = f2u(h[3]);
        unsigned hp0 = __builtin_amdgcn_perm(u1, u0, 0x07060302u);
        unsigned hp1 = __builtin_amdgcn_perm(u3, u2, 0x07060302u);
        float l0 = h[0] - u2f(u0 & 0xffff0000u);
        float l1 = h[1] - u2f(u1 & 0xffff0000u);
        float l2 = h[2] - u2f(u2 & 0xffff0000u);
        float l3 = h[3] - u2f(u3 & 0xffff0000u);
        unsigned lp0 = __builtin_amdgcn_perm(f2u(l1), f2u(l0), 0x07060302u);
        unsigned lp1 = __builtin_amdgcn_perm(f2u(l3), f2u(l2), 0x07060302u);

        // rebuild B fragments for t+1 via cross-lane pulls (no LDS round trip)
        uintx4 bh4, bl4;
        bh4[0] = (unsigned)__builtin_amdgcn_ds_bpermute(a1, (int)hp0);
        bh4[1] = (unsigned)__builtin_amdgcn_ds_bpermute(a1, (int)hp1);
        bh4[2] = (unsigned)__builtin_amdgcn_ds_bpermute(a2, (int)hp0);
        bh4[3] = (unsigned)__builtin_amdgcn_ds_bpermute(a2, (int)hp1);
        bl4[0] = (unsigned)__builtin_amdgcn_ds_bpermute(a1, (int)lp0);
        bl4[1] = (unsigned)__builtin_amdgcn_ds_bpermute(a1, (int)lp1);
        bl4[2] = (unsigned)__builtin_amdgcn_ds_bpermute(a2, (int)lp0);
        bl4[3] = (unsigned)__builtin_amdgcn_ds_bpermute(a2, (int)lp1);
        Bhi = __builtin_bit_cast(short8, bh4);
        Blo = __builtin_bit_cast(short8, bl4);
        c = cn;
    }

    // ---- epilogue: FC over [u, mean(h)] ; lane owns 4 dims of sample col ----
    float4 fc1 = *(const float4*)&fc_W[quad * 4];
    float4 fc2 = *(const float4*)&fc_W[16 + quad * 4];
    int uid = user_id[sampBase + col];
    float4 u4 = *(const float4*)&user_emb[(long long)uid * 16 + quad * 4];
    const float inv64 = 1.0f / 64.0f;
    float val = fc1.x * u4.x + fc1.y * u4.y + fc1.z * u4.z + fc1.w * u4.w;
    val = fmaf(fc2.x * inv64, pool[0], val);
    val = fmaf(fc2.y * inv64, pool[1], val);
    val = fmaf(fc2.z * inv64, pool[2], val);
    val = fmaf(fc2.w * inv64, pool[3], val);
    val += __shfl_xor(val, 16);
    val += __shfl_xor(val, 32);
    if (quad == 0) out[sampBase + col] = val + fc_b[0];
}

extern "C" void kernel_launch(void* const* d_in, const int* in_sizes, int n_in,
                              void* d_out, int out_size, void* d_ws, size_t ws_size,
                              hipStream_t stream) {
    const int*   user_id    = (const int*)d_in[0];
    const int*   launch_seq = (const int*)d_in[1];
    const float* user_emb   = (const float*)d_in[2];
    const float* launch_emb = (const float*)d_in[3];
    const float* W_ih       = (const float*)d_in[4];
    const float* W_hh       = (const float*)d_in[5];
    const float* b_ih       = (const float*)d_in[6];
    const float* b_hh       = (const float*)d_in[7];
    const float* fc_W       = (const float*)d_in[8];
    const float* fc_b       = (const float*)d_in[9];
    float* out = (float*)d_out;

    gru_mfma<<<dim3(NBLK), dim3(64), 0, stream>>>(
        user_id, launch_seq, user_emb, launch_emb,
        W_ih, W_hh, b_ih, b_hh, fc_W, fc_b, out);
}

// Round 5
// 133.660 us; speedup vs baseline: 1.1595x; 1.0333x over previous
//
#include <hip/hip_runtime.h>
#include <hip/hip_bf16.h>
#include <string.h>

// GRU recommender via MFMA, R5: B=32768, T=64, H=16, launch vocab=3.
// One wave per block, TWO independent 16-sample chains per wave (32 samples),
// 1024 blocks -> 1 wave/SIMD; the 2 chains give in-wave ILP to hide the
// bpermute->MFMA->transcendental serial chain that left 43% idle in R4.
//
// D[g][s] = W[g][:] . h[:][s]:  A = W_hh (static, RNE hi/lo split),
// B = h (RNE bf16, hi plane ONLY; W stays split so gh = W_fp32 * h_bf16).
// gx TRICK: A rows k=16..18 carry the 3-code gx LUT (hi+lo), k=19 carries
// L2*b_hh_n; B rows k=16..19 are a per-sample one-hot (2 constant dwords
// selected by the code) -> the MFMA adds gx/b_hh itself, C-init is zero,
// and the r/z sel3 cndmask tree disappears. Only n keeps a 3-way select
// (gx_n is added outside r*gh_n). A rows k>=20 are zero -> B garbage there
// is harmless.
// Per chain-step: 6 MFMA + 4 ds_bpermute + 1 ds_read_u8 + gates.
// Numerics: everything RNE (truncation bias in R3/R4 cost 30x accuracy);
// h bf16-only predicted absmax ~1e-2 vs 5.4e-2 threshold. Fallback: h-lo.

#define NBLK 1024  // 32768 / 32

typedef __attribute__((ext_vector_type(8))) short    short8;
typedef __attribute__((ext_vector_type(4))) float    floatx4;
typedef __attribute__((ext_vector_type(4))) unsigned uintx4;

static __device__ __forceinline__ float fexp2(float x) { return __builtin_amdgcn_exp2f(x); }
static __device__ __forceinline__ float frcp(float x)  { return __builtin_amdgcn_rcpf(x); }
static __device__ __forceinline__ unsigned short bfrne(float f) {
    union { __hip_bfloat16 b; unsigned short u; } cv; cv.b = __float2bfloat16(f); return cv.u;
}
static __device__ __forceinline__ float bf2f(unsigned short u) {
    unsigned v = ((unsigned)u) << 16; float f; memcpy(&f, &v, 4); return f;
}
static __device__ __forceinline__ unsigned pkbf(float a, float b) {
    return (unsigned)bfrne(a) | ((unsigned)bfrne(b) << 16);
}
static __device__ __forceinline__ float sel3(int c, float a0, float a1, float a2) {
    return c == 0 ? a0 : (c == 1 ? a1 : a2);
}

__global__ __launch_bounds__(64) void gru_mfma(
    const int* __restrict__ user_id,
    const int* __restrict__ launch_seq,
    const float* __restrict__ user_emb,
    const float* __restrict__ launch_emb,
    const float* __restrict__ W_ih,
    const float* __restrict__ W_hh,
    const float* __restrict__ b_ih,
    const float* __restrict__ b_hh,
    const float* __restrict__ fc_W,
    const float* __restrict__ fc_b,
    float* __restrict__ out)
{
    constexpr float L  = 1.4426950408889634f;   // log2(e)
    constexpr float L2 = 2.8853900817779268f;   // 2*log2(e)

    __shared__ float         gxlut[144];    // [(gate*3+code)*16 + dim]
    __shared__ unsigned char seqT[2048];    // [t*32 + sample32]

    const int tid  = threadIdx.x;
    const int col  = tid & 15;
    const int quad = tid >> 4;
    const bool isq2 = (quad == 2);
    const long long sampBase = (long long)blockIdx.x * 32;

    // ---- stage launch_seq transposed: seqT[t*32 + s], s in [0,32) ----
    {
        int r = tid >> 1, w = tid & 1;
        const int* sp = launch_seq + (sampBase + r) * 64 + w * 32;
        #pragma unroll
        for (int g = 0; g < 8; ++g) {
            int4 v = ((const int4*)sp)[g];
            int t0 = w * 32 + g * 4;
            seqT[(t0 + 0) * 32 + r] = (unsigned char)v.x;
            seqT[(t0 + 1) * 32 + r] = (unsigned char)v.y;
            seqT[(t0 + 2) * 32 + r] = (unsigned char)v.z;
            seqT[(t0 + 3) * 32 + r] = (unsigned char)v.w;
        }
    }

    // ---- gx LUT: 3 codes x 48 gates, pre-scaled ----
    for (int idx = tid; idx < 144; idx += 64) {
        int s = idx / 48, g = idx - s * 48;
        float dot = b_ih[g];
        #pragma unroll
        for (int k = 0; k < 16; ++k)
            dot = fmaf(W_ih[g * 16 + k], launch_emb[s * 16 + k], dot);
        int gate = g >> 4, dim = g & 15;
        gxlut[(gate * 3 + s) * 16 + dim] =
            (g < 32) ? (-L * (dot + b_hh[g])) : (L2 * dot);
    }

    __syncthreads();   // gxlut + seqT visible (A build reads gxlut)

    // ---- A fragments: W rows (quads 0,1), gx/bias rows (quad 2), zero (quad 3) ----
    short8 Wrh, Wrl, Wzh, Wzl, Wnh, Wnl;
    {
        auto makeW = [&](int goff, float scale, const float* gx3, float extra19,
                         short8& Hi, short8& Lo) {
            float w[8];
            #pragma unroll
            for (int j = 0; j < 8; ++j) w[j] = 0.f;
            if (quad < 2) {
                const float* row = W_hh + (goff + col) * 16 + quad * 8;
                #pragma unroll
                for (int j = 0; j < 8; ++j) w[j] = scale * row[j];
            } else if (quad == 2) {
                if (gx3) { w[0] = gx3[col]; w[1] = gx3[16 + col]; w[2] = gx3[32 + col]; }
                w[3] = extra19;
            }
            uintx4 hi, lo;
            #pragma unroll
            for (int p = 0; p < 4; ++p) {
                unsigned short h0 = bfrne(w[2 * p]), h1 = bfrne(w[2 * p + 1]);
                hi[p] = (unsigned)h0 | ((unsigned)h1 << 16);
                lo[p] = pkbf(w[2 * p] - bf2f(h0), w[2 * p + 1] - bf2f(h1));
            }
            Hi = __builtin_bit_cast(short8, hi);
            Lo = __builtin_bit_cast(short8, lo);
        };
        makeW(0,  -L, &gxlut[0],  0.f,                  Wrh, Wrl);
        makeW(16, -L, &gxlut[48], 0.f,                  Wzh, Wzl);
        makeW(32,  L2, (const float*)0, L2 * b_hh[32 + col], Wnh, Wnl);
    }

    // ---- per-lane gx_n LUT (n-gate is added outside r*gh_n) ----
    floatx4 gn0 = *(const floatx4*)&gxlut[(6 + 0) * 16 + quad * 4];
    floatx4 gn1 = *(const floatx4*)&gxlut[(6 + 1) * 16 + quad * 4];
    floatx4 gn2 = *(const floatx4*)&gxlut[(6 + 2) * 16 + quad * 4];

    // bpermute source byte-addresses (loop-invariant, shared by both chains)
    const int a1 = (col + 32 * (quad & 1)) * 4;
    const int a2 = a1 + 64;

    // ---- chain state (L: samples base+0..15, R: base+16..31) ----
    floatx4 hL = {0,0,0,0}, poolL = {0,0,0,0};
    floatx4 hR = {0,0,0,0}, poolR = {0,0,0,0};
    int cL = seqT[col];
    int cR = seqT[16 + col];
    short8 BL, BR;
    {
        unsigned P0 = (cL == 0 ? 0x3F80u : 0u) | (cL == 1 ? 0x3F800000u : 0u);
        unsigned P1 = (cL == 2 ? 0x3F80u : 0u) | 0x3F800000u;
        uintx4 b = {isq2 ? P0 : 0u, isq2 ? P1 : 0u, 0u, 0u};
        BL = __builtin_bit_cast(short8, b);
        P0 = (cR == 0 ? 0x3F80u : 0u) | (cR == 1 ? 0x3F800000u : 0u);
        P1 = (cR == 2 ? 0x3F80u : 0u) | 0x3F800000u;
        uintx4 b2 = {isq2 ? P0 : 0u, isq2 ? P1 : 0u, 0u, 0u};
        BR = __builtin_bit_cast(short8, b2);
    }

    const floatx4 CZ = {0.f, 0.f, 0.f, 0.f};

    auto step = [&](floatx4& h, floatx4& pool, short8& B, int& c, int base, int t) {
        floatx4 accr = __builtin_amdgcn_mfma_f32_16x16x32_bf16(Wrh, B, CZ, 0, 0, 0);
        floatx4 accz = __builtin_amdgcn_mfma_f32_16x16x32_bf16(Wzh, B, CZ, 0, 0, 0);
        floatx4 accn = __builtin_amdgcn_mfma_f32_16x16x32_bf16(Wnh, B, CZ, 0, 0, 0);
        accr = __builtin_amdgcn_mfma_f32_16x16x32_bf16(Wrl, B, accr, 0, 0, 0);
        accz = __builtin_amdgcn_mfma_f32_16x16x32_bf16(Wzl, B, accz, 0, 0, 0);
        accn = __builtin_amdgcn_mfma_f32_16x16x32_bf16(Wnl, B, accn, 0, 0, 0);

        int cn = seqT[((t + 1) & 63) * 32 + base + col];   // code for t+1

        #pragma unroll
        for (int i = 0; i < 4; ++i) {
            float gnv = sel3(c, gn0[i], gn1[i], gn2[i]);
            float r  = frcp(1.0f + fexp2(accr[i]));
            float z  = frcp(1.0f + fexp2(accz[i]));
            float y  = fmaf(r, accn[i], gnv);
            float n  = fmaf(-2.0f, frcp(1.0f + fexp2(y)), 1.0f);
            float hn = fmaf(z, h[i] - n, n);
            h[i] = hn;
            pool[i] += hn;
        }

        // pack RNE bf16 (hi plane only) and rebuild B for t+1
        unsigned hp0 = pkbf(h[0], h[1]);
        unsigned hp1 = pkbf(h[2], h[3]);
        unsigned P0 = (cn == 0 ? 0x3F80u : 0u) | (cn == 1 ? 0x3F800000u : 0u);
        unsigned P1 = (cn == 2 ? 0x3F80u : 0u) | 0x3F800000u;
        uintx4 b;
        b[0] = (unsigned)__builtin_amdgcn_ds_bpermute(a1, (int)hp0);
        b[1] = (unsigned)__builtin_amdgcn_ds_bpermute(a1, (int)hp1);
        b[2] = (unsigned)__builtin_amdgcn_ds_bpermute(a2, (int)hp0);
        b[3] = (unsigned)__builtin_amdgcn_ds_bpermute(a2, (int)hp1);
        b[0] = isq2 ? P0 : b[0];   // one-hot rows k=16..19
        b[1] = isq2 ? P1 : b[1];
        B = __builtin_bit_cast(short8, b);
        c = cn;
    };

    #pragma unroll 2
    for (int t = 0; t < 64; ++t) {
        step(hL, poolL, BL, cL, 0, t);
        step(hR, poolR, BR, cR, 16, t);
    }

    // ---- epilogue: FC over [u, mean(h)] for both chains ----
    float4 fc1 = *(const float4*)&fc_W[quad * 4];
    float4 fc2 = *(const float4*)&fc_W[16 + quad * 4];
    const float inv64 = 1.0f / 64.0f;
    #pragma unroll
    for (int chain = 0; chain < 2; ++chain) {
        const floatx4& pool = chain ? poolR : poolL;
        long long s = sampBase + chain * 16 + col;
        int uid = user_id[s];
        float4 u4 = *(const float4*)&user_emb[(long long)uid * 16 + quad * 4];
        float val = fc1.x * u4.x + fc1.y * u4.y + fc1.z * u4.z + fc1.w * u4.w;
        val = fmaf(fc2.x * inv64, pool[0], val);
        val = fmaf(fc2.y * inv64, pool[1], val);
        val = fmaf(fc2.z * inv64, pool[2], val);
        val = fmaf(fc2.w * inv64, pool[3], val);
        val += __shfl_xor(val, 16);
        val += __shfl_xor(val, 32);
        if (quad == 0) out[s] = val + fc_b[0];
    }
}

extern "C" void kernel_launch(void* const* d_in, const int* in_sizes, int n_in,
                              void* d_out, int out_size, void* d_ws, size_t ws_size,
                              hipStream_t stream) {
    const int*   user_id    = (const int*)d_in[0];
    const int*   launch_seq = (const int*)d_in[1];
    const float* user_emb   = (const float*)d_in[2];
    const float* launch_emb = (const float*)d_in[3];
    const float* W_ih       = (const float*)d_in[4];
    const float* W_hh       = (const float*)d_in[5];
    const float* b_ih       = (const float*)d_in[6];
    const float* b_hh       = (const float*)d_in[7];
    const float* fc_W       = (const float*)d_in[8];
    const float* fc_b       = (const float*)d_in[9];
    float* out = (float*)d_out;

    gru_mfma<<<dim3(NBLK), dim3(64), 0, stream>>>(
        user_id, launch_seq, user_emb, launch_emb,
        W_ih, W_hh, b_ih, b_hh, fc_W, fc_b, out);
}